// Round 7
// baseline (223.086 us; speedup 1.0000x reference)
//
#include <hip/hip_runtime.h>
#include <stdint.h>

typedef __attribute__((ext_vector_type(4))) float f32x4;
typedef __attribute__((ext_vector_type(8))) short s16x8;

#define BB 4
#define NN 4096
#define FF 32
#define BNF (BB*NN*FF)   // 524288

// ---------- bf16 helpers ----------
static __device__ __forceinline__ float bf2f(uint16_t u) {
    union { uint32_t i; float f; } v; v.i = ((uint32_t)u) << 16; return v.f;
}
static __device__ __forceinline__ uint16_t f2bf(float f) {
    union { float f; uint32_t i; } v; v.f = f;
    uint32_t r = v.i + 0x7FFFu + ((v.i >> 16) & 1u);
    return (uint16_t)(r >> 16);
}
static __device__ __forceinline__ float sig_acc(float x) { return 1.0f / (1.0f + expf(-x)); }

// ---------- adj fp32 -> bf16 (once; both GEMMs read bf16, LLC-resident after) ----------
__global__ __launch_bounds__(256) void cvt_adj(const float* __restrict__ a,
                                               uint16_t* __restrict__ ab)
{
    size_t i = ((size_t)blockIdx.x * 256 + threadIdx.x) * 8;   // grid 8192
    float4 v0 = *(const float4*)(a + i);
    float4 v1 = *(const float4*)(a + i + 4);
    union { uint4 u; uint16_t e[8]; } o;
    o.e[0] = f2bf(v0.x); o.e[1] = f2bf(v0.y); o.e[2] = f2bf(v0.z); o.e[3] = f2bf(v0.w);
    o.e[4] = f2bf(v1.x); o.e[5] = f2bf(v1.y); o.e[6] = f2bf(v1.z); o.e[7] = f2bf(v1.w);
    *(uint4*)(ab + i) = o.u;
}

// ---------- pack: state [B][N][F] fp32 -> dst[tensor*128 + b*32 + f][n] bf16 ----------
__global__ __launch_bounds__(256) void pack_kernel(
    const float* __restrict__ s0, const float* __restrict__ s1,
    uint16_t* __restrict__ dst)
{
    int bid = blockIdx.x;
    int tensor = bid >> 8;
    int b = (bid >> 6) & 3;
    int ntile = bid & 63;
    const float* src = tensor ? s1 : s0;
    int n0 = ntile * 64;
    __shared__ uint16_t tl[32][65];
    int t = threadIdx.x;
    {
        int i = t >> 2, ch = t & 3;
        size_t idx = ((size_t)(b * NN + n0 + i)) * FF + ch * 8;
        float4 v0 = *(const float4*)(src + idx);
        float4 v1 = *(const float4*)(src + idx + 4);
        uint16_t e[8] = { f2bf(v0.x), f2bf(v0.y), f2bf(v0.z), f2bf(v0.w),
                          f2bf(v1.x), f2bf(v1.y), f2bf(v1.z), f2bf(v1.w) };
        #pragma unroll
        for (int k = 0; k < 8; k++) tl[ch * 8 + k][i] = e[k];
    }
    __syncthreads();
    {
        int f = t >> 3, ch = t & 7;
        union { uint4 u; uint16_t e[8]; } v;
        #pragma unroll
        for (int k = 0; k < 8; k++) v.e[k] = tl[f][ch * 8 + k];
        size_t row = (size_t)(tensor * 128 + b * 32 + f);
        *(uint4*)(dst + row * NN + n0 + ch * 8) = v.u;
    }
}

// ---------- GEMM: sum_k adj[m][k]*Bt[c][k]; partials [ks][m][c] (coalesced) ----------
// 128x128 tile, BK=32, 4 waves (2x2 of 64x64), 16x16x32 bf16 MFMA
// register-prefetch double-buffer on the staging loads
__global__ __launch_bounds__(256) void gemm_kernel(
    const void* __restrict__ Av,      // adj: bf16 (isf32A=0) or fp32 (isf32A=1)
    const uint16_t* __restrict__ Bt,  // [256][4096] bf16
    float* __restrict__ part,         // [ns][4096][256] fp32
    uint16_t* __restrict__ Cb,        // [4096][256] bf16 (direct fallback)
    int kLen, int direct, int isf32A)
{
    int mt = blockIdx.x, nt = blockIdx.y, ks = blockIdx.z;
    int m0 = mt * 128, c0 = nt * 128, k0 = ks * kLen;
    int kend = k0 + kLen;
    __shared__ __align__(16) uint16_t aL[128 * 32];
    __shared__ __align__(16) uint16_t bL[128 * 32];
    int t = threadIdx.x;
    int lane = t & 63, w = t >> 6;
    int wm = (w & 1) * 64, wn = (w >> 1) * 64;
    int lm = lane & 15, lk = lane >> 4;

    const uint16_t* A16 = (const uint16_t*)Av;
    const float*    Af  = (const float*)Av;

    // staging geometry: thread t covers two 16B chunks of the 8KB tile
    int pos0 = t * 16, pos1 = 4096 + t * 16;
    int row0 = pos0 >> 6, col0 = (pos0 & 63) >> 1;
    int row1 = pos1 >> 6, col1 = (pos1 & 63) >> 1;

    f32x4 acc[4][4] = {};
    union { uint4 u; uint16_t e[8]; } va[2], vb[2];

    // prologue load (kk = k0)
    {
        size_t a0 = (size_t)(m0 + row0) * 4096 + k0 + col0;
        size_t a1 = (size_t)(m0 + row1) * 4096 + k0 + col1;
        size_t b0 = (size_t)(c0 + row0) * 4096 + k0 + col0;
        size_t b1 = (size_t)(c0 + row1) * 4096 + k0 + col1;
        if (!isf32A) {
            va[0].u = *(const uint4*)(A16 + a0);
            va[1].u = *(const uint4*)(A16 + a1);
        } else {
            union { uint4 u[2]; float f[8]; } w0, w1;
            w0.u[0] = *(const uint4*)(Af + a0); w0.u[1] = *(const uint4*)(Af + a0 + 4);
            w1.u[0] = *(const uint4*)(Af + a1); w1.u[1] = *(const uint4*)(Af + a1 + 4);
            #pragma unroll
            for (int k = 0; k < 8; k++) { va[0].e[k] = f2bf(w0.f[k]); va[1].e[k] = f2bf(w1.f[k]); }
        }
        vb[0].u = *(const uint4*)(Bt + b0);
        vb[1].u = *(const uint4*)(Bt + b1);
    }

    for (int kk = k0; kk < kend; kk += 32) {
        if (kk != k0) __syncthreads();           // protect prior ds_reads
        *(uint4*)((char*)aL + pos0) = va[0].u;
        *(uint4*)((char*)aL + pos1) = va[1].u;
        *(uint4*)((char*)bL + pos0) = vb[0].u;
        *(uint4*)((char*)bL + pos1) = vb[1].u;
        __syncthreads();

        int kn = kk + 32;
        if (kn < kend) {                         // prefetch next tile (hidden behind MFMAs)
            size_t a0 = (size_t)(m0 + row0) * 4096 + kn + col0;
            size_t a1 = (size_t)(m0 + row1) * 4096 + kn + col1;
            size_t b0 = (size_t)(c0 + row0) * 4096 + kn + col0;
            size_t b1 = (size_t)(c0 + row1) * 4096 + kn + col1;
            if (!isf32A) {
                va[0].u = *(const uint4*)(A16 + a0);
                va[1].u = *(const uint4*)(A16 + a1);
            } else {
                union { uint4 u[2]; float f[8]; } w0, w1;
                w0.u[0] = *(const uint4*)(Af + a0); w0.u[1] = *(const uint4*)(Af + a0 + 4);
                w1.u[0] = *(const uint4*)(Af + a1); w1.u[1] = *(const uint4*)(Af + a1 + 4);
                #pragma unroll
                for (int k = 0; k < 8; k++) { va[0].e[k] = f2bf(w0.f[k]); va[1].e[k] = f2bf(w1.f[k]); }
            }
            vb[0].u = *(const uint4*)(Bt + b0);
            vb[1].u = *(const uint4*)(Bt + b1);
        }

        s16x8 af[4], bfr[4];
        #pragma unroll
        for (int i = 0; i < 4; i++)
            af[i] = *(const s16x8*)(aL + (wm + i * 16 + lm) * 32 + lk * 8);
        #pragma unroll
        for (int j = 0; j < 4; j++)
            bfr[j] = *(const s16x8*)(bL + (wn + j * 16 + lm) * 32 + lk * 8);
        #pragma unroll
        for (int i = 0; i < 4; i++)
            #pragma unroll
            for (int j = 0; j < 4; j++)
                acc[i][j] = __builtin_amdgcn_mfma_f32_16x16x32_bf16(af[i], bfr[j], acc[i][j], 0, 0, 0);
    }

    // C/D layout: col(lane&15)->c, row((lane>>4)*4+reg)->m. Store [m][c]: lanes
    // consecutive in c => 64B-coalesced scalar stores.
    int r4 = (lane >> 4) * 4;
    if (direct) {
        #pragma unroll
        for (int i = 0; i < 4; i++)
            #pragma unroll
            for (int j = 0; j < 4; j++) {
                int c = c0 + wn + j * 16 + lm;
                int mrb = m0 + wm + i * 16 + r4;
                #pragma unroll
                for (int r = 0; r < 4; r++)
                    Cb[(size_t)(mrb + r) * 256 + c] = f2bf(acc[i][j][r]);
            }
    } else {
        #pragma unroll
        for (int i = 0; i < 4; i++)
            #pragma unroll
            for (int j = 0; j < 4; j++) {
                int c = c0 + wn + j * 16 + lm;
                int mrb = m0 + wm + i * 16 + r4;
                #pragma unroll
                for (int r = 0; r < 4; r++)
                    part[((size_t)ks * 4096 + mrb + r) * 256 + c] = acc[i][j][r];
            }
    }
}

// ---------- fuse staging: sum split-K partials [ks][m][c] into AL[node][64] ----------
// fa<32: c = b*32+fa (first operand); fa>=32: c = 128+b*32+fa-32 (second operand)
static __device__ __forceinline__ void stage_acts(
    const float* __restrict__ part, const uint16_t* __restrict__ Cb, int ns,
    int b, int n0, int t, float AL[32][65])
{
    int node = t >> 3, q = t & 7;
    int fa0 = q * 8;
    int cbase = (fa0 < 32) ? (b * 32 + fa0) : (128 + b * 32 + (fa0 - 32));
    float s[8] = {};
    if (ns) {
        for (int k = 0; k < ns; k++) {
            const float* p = part + ((size_t)k * 4096 + n0 + node) * 256 + cbase;
            float4 v0 = *(const float4*)p;
            float4 v1 = *(const float4*)(p + 4);
            s[0] += v0.x; s[1] += v0.y; s[2] += v0.z; s[3] += v0.w;
            s[4] += v1.x; s[5] += v1.y; s[6] += v1.z; s[7] += v1.w;
        }
    } else {
        union { uint4 u; uint16_t e[8]; } v;
        v.u = *(const uint4*)(Cb + ((size_t)(n0 + node)) * 256 + cbase);
        #pragma unroll
        for (int k = 0; k < 8; k++) s[k] = bf2f(v.e[k]);
    }
    #pragma unroll
    for (int k = 0; k < 8; k++) AL[node][fa0 + k] = s[k];
}

// ---------- fuse1: 8-gate GLU + LSTM update; c_new (fp32) + packed h1 (bf16) ----------
__global__ __launch_bounds__(256) void fuse1_kernel(
    const float* __restrict__ part, const uint16_t* __restrict__ Cb, int ns,
    const float* __restrict__ Wf, const float* __restrict__ bf_,
    const float* __restrict__ cf,
    float* __restrict__ cnew, uint16_t* __restrict__ S2t)
{
    __shared__ uint32_t WL[8 * 32 * 32];
    __shared__ float BL[8 * 64];
    __shared__ float AL[32][65];
    __shared__ uint16_t H1[32][33];

    int t = threadIdx.x;
    int bid = blockIdx.x;
    int b = bid >> 7, ntile = bid & 127;
    int n0 = ntile * 32;

    for (int i = t; i < 8192; i += 256) {
        int g = i >> 10, rem = i & 1023, f = rem >> 5, j = rem & 31;
        uint32_t lo = f2bf(Wf[g * 2048 + f * 64 + j]);
        uint32_t hi = f2bf(Wf[g * 2048 + f * 64 + 32 + j]);
        WL[i] = lo | (hi << 16);
    }
    if (t < 128) {
        #pragma unroll
        for (int k = 0; k < 4; k++) BL[t * 4 + k] = bf_[t * 4 + k];
    }
    stage_acts(part, Cb, ns, b, n0, t, AL);
    __syncthreads();

    int j = t & 31, nb = t >> 5;
    float acc[4][16];
    #pragma unroll
    for (int u = 0; u < 4; u++)
        #pragma unroll
        for (int g = 0; g < 8; g++) {
            acc[u][g * 2]     = BL[g * 64 + j];
            acc[u][g * 2 + 1] = BL[g * 64 + 32 + j];
        }
    #pragma unroll 2
    for (int f = 0; f < 32; f++) {
        float wls[8], wrs[8];
        #pragma unroll
        for (int g = 0; g < 8; g++) {
            uint32_t wv = WL[g * 1024 + f * 32 + j];
            wls[g] = __uint_as_float(wv << 16);
            wrs[g] = __uint_as_float(wv & 0xFFFF0000u);
        }
        #pragma unroll
        for (int u = 0; u < 4; u++) {
            int node = nb + u * 8;
            float ax = AL[node][f], ah = AL[node][32 + f];
            #pragma unroll
            for (int g = 0; g < 8; g++) {
                float src = (g & 1) ? ah : ax;
                acc[u][g * 2]     += src * wls[g];
                acc[u][g * 2 + 1] += src * wrs[g];
            }
        }
    }
    #pragma unroll
    for (int u = 0; u < 4; u++) {
        int node = nb + u * 8;
        float fx = acc[u][0]  * sig_acc(acc[u][1]);
        float fh = acc[u][2]  * sig_acc(acc[u][3]);
        float ix = acc[u][4]  * sig_acc(acc[u][5]);
        float ih = acc[u][6]  * sig_acc(acc[u][7]);
        float cx = acc[u][8]  * sig_acc(acc[u][9]);
        float ch = acc[u][10] * sig_acc(acc[u][11]);
        float ox = acc[u][12] * sig_acc(acc[u][13]);
        float oh = acc[u][14] * sig_acc(acc[u][15]);
        float fg = sig_acc(fx + fh), ig = sig_acc(ix + ih), og = sig_acc(ox + oh);
        size_t gidx = ((size_t)(b * NN + n0 + node)) * FF + j;
        float cvv = cf[gidx];
        float cn = fg * cvv + ig * tanhf(cx + ch);
        float h1 = og * tanhf(cn);
        cnew[gidx] = cn;
        H1[j][node] = f2bf(h1);
    }
    __syncthreads();
    {
        int fr = t >> 3, ch = t & 7;
        union { uint2 u; uint16_t e[4]; } v;
        #pragma unroll
        for (int k = 0; k < 4; k++) v.e[k] = H1[fr][ch * 4 + k];
        *(uint2*)(S2t + ((size_t)(b * 32 + fr)) * NN + n0 + ch * 4) = v.u;
    }
}

// ---------- fuse2: 6-gate GLU + memory-state update; h_new, m_new (fp32) ----------
__global__ __launch_bounds__(256) void fuse2_kernel(
    const float* __restrict__ part, const uint16_t* __restrict__ Cb, int ns,
    const float* __restrict__ Wf, const float* __restrict__ bf_,
    const float* __restrict__ mf,
    float* __restrict__ hnew, float* __restrict__ mnew)
{
    __shared__ uint32_t WL[6 * 32 * 32];
    __shared__ float BL[6 * 64];
    __shared__ float AL[32][65];

    int t = threadIdx.x;
    int bid = blockIdx.x;
    int b = bid >> 7, ntile = bid & 127;
    int n0 = ntile * 32;

    for (int i = t; i < 6144; i += 256) {
        int g = i >> 10, rem = i & 1023, f = rem >> 5, j = rem & 31;
        int gg = 8 + g;
        uint32_t lo = f2bf(Wf[gg * 2048 + f * 64 + j]);
        uint32_t hi = f2bf(Wf[gg * 2048 + f * 64 + 32 + j]);
        WL[i] = lo | (hi << 16);
    }
    if (t < 96) {
        #pragma unroll
        for (int k = 0; k < 4; k++) BL[t * 4 + k] = bf_[512 + t * 4 + k];
    }
    stage_acts(part, Cb, ns, b, n0, t, AL);
    __syncthreads();

    int j = t & 31, nb = t >> 5;
    float acc[4][12];
    #pragma unroll
    for (int u = 0; u < 4; u++)
        #pragma unroll
        for (int g = 0; g < 6; g++) {
            acc[u][g * 2]     = BL[g * 64 + j];
            acc[u][g * 2 + 1] = BL[g * 64 + 32 + j];
        }
    #pragma unroll 2
    for (int f = 0; f < 32; f++) {
        float wls[6], wrs[6];
        #pragma unroll
        for (int g = 0; g < 6; g++) {
            uint32_t wv = WL[g * 1024 + f * 32 + j];
            wls[g] = __uint_as_float(wv << 16);
            wrs[g] = __uint_as_float(wv & 0xFFFF0000u);
        }
        #pragma unroll
        for (int u = 0; u < 4; u++) {
            int node = nb + u * 8;
            float ah1 = AL[node][f], am = AL[node][32 + f];
            #pragma unroll
            for (int g = 0; g < 6; g++) {
                float src = (g & 1) ? am : ah1;
                acc[u][g * 2]     += src * wls[g];
                acc[u][g * 2 + 1] += src * wrs[g];
            }
        }
    }
    #pragma unroll
    for (int u = 0; u < 4; u++) {
        int node = nb + u * 8;
        float sa_ih = acc[u][0]  * sig_acc(acc[u][1]);
        float sa_im = acc[u][2]  * sig_acc(acc[u][3]);
        float sa_gh = acc[u][4]  * sig_acc(acc[u][5]);
        float sa_gm = acc[u][6]  * sig_acc(acc[u][7]);
        float sa_oh = acc[u][8]  * sig_acc(acc[u][9]);
        float sa_om = acc[u][10] * sig_acc(acc[u][11]);
        float i2 = sig_acc(sa_ih + sa_im);
        float g2 = sig_acc(sa_gh + sa_gm);
        float o2 = sig_acc(sa_oh + sa_om);
        size_t gidx = ((size_t)(b * NN + n0 + node)) * FF + j;
        float mvv = mf[gidx];
        float mn = i2 * mvv + (1.0f - i2) * g2;
        float hn = mn * o2;
        mnew[gidx] = mn;
        hnew[gidx] = hn;
    }
}

extern "C" void kernel_launch(void* const* d_in, const int* in_sizes, int n_in,
                              void* d_out, int out_size, void* d_ws, size_t ws_size,
                              hipStream_t stream) {
    (void)in_sizes; (void)n_in; (void)out_size;
    const float* x   = (const float*)d_in[0];
    const float* h   = (const float*)d_in[1];
    const float* c   = (const float*)d_in[2];
    const float* m   = (const float*)d_in[3];
    const float* adj = (const float*)d_in[4];
    const float* W   = (const float*)d_in[5];
    const float* bb  = (const float*)d_in[6];
    float* out = (float*)d_out;

    char* ws = (char*)d_ws;
    int haveAdjb = ws_size >= (size_t)(40u << 20);
    uint16_t* adjb = (uint16_t*)ws;                              // 32 MB (tier A)
    size_t pOff = haveAdjb ? (size_t)(32u << 20) : 0;
    uint16_t* P    = (uint16_t*)(ws + pOff);                     // 2 MB packed B
    uint16_t* Cbuf = (uint16_t*)(ws + pOff + (2u << 20));        // 2 MB direct out
    size_t partOff = pOff + (4u << 20);
    float* part = (float*)(ws + partOff);

    if (ws_size < (4u << 20)) return;
    size_t avail = ws_size - partOff;
    int ns = 0;
    if      (avail >= (size_t)(32u << 20)) ns = 8;
    else if (avail >= (size_t)(16u << 20)) ns = 4;
    else if (avail >= (size_t)( 8u << 20)) ns = 2;
    else if (avail >= (size_t)( 4u << 20)) ns = 1;

    const void* Agemm = haveAdjb ? (const void*)adjb : (const void*)adj;
    int isf32A = haveAdjb ? 0 : 1;
    int nsG = ns ? ns : 1;
    int directG = ns ? 0 : 1;

    if (haveAdjb) cvt_adj<<<8192, 256, 0, stream>>>(adj, adjb);

    // phase 1: pack x,h -> P rows 0..255; GEMM1 partials; fuse1 sums + cell update
    pack_kernel<<<512, 256, 0, stream>>>(x, h, P);
    gemm_kernel<<<dim3(32, 2, nsG), 256, 0, stream>>>(Agemm, P, part, Cbuf, 4096 / nsG, directG, isf32A);
    fuse1_kernel<<<512, 256, 0, stream>>>(part, Cbuf, ns, W, bb, c, out + BNF, P);
    // pack m into P rows 128..255 (h1 already packed into rows 0..127 by fuse1)
    pack_kernel<<<256, 256, 0, stream>>>(m, m, P + (size_t)128 * NN);
    // phase 2
    gemm_kernel<<<dim3(32, 2, nsG), 256, 0, stream>>>(Agemm, P, part, Cbuf, 4096 / nsG, directG, isf32A);
    fuse2_kernel<<<512, 256, 0, stream>>>(part, Cbuf, ns, W, bb, m, out, out + 2 * BNF);
}